// Round 5
// baseline (1047.539 us; speedup 1.0000x reference)
//
#include <hip/hip_runtime.h>
#include <cstdint>
#include <cstddef>

#define Bx 2
#define Sx 1024
#define Dx 1024
#define Hx 16
#define Lx 4
#define FFx 2048
#define DKx 64
#define Mx (Bx * Sx)   // 2048 rows

typedef __attribute__((ext_vector_type(4))) float f32x4;
typedef __attribute__((ext_vector_type(8))) __bf16 bf16x8;

// ---------------- embed + positional encoding (pe indexed by BATCH, per ref bug) ----------------
__global__ void embed_kernel(const int* __restrict__ tokens,
                             const float* __restrict__ emb,
                             float* __restrict__ x, __bf16* __restrict__ xb) {
  size_t i = (size_t)blockIdx.x * blockDim.x + threadIdx.x;  // over Mx*Dx
  if (i >= (size_t)Mx * Dx) return;
  int d = (int)(i % Dx);
  size_t bs = i / Dx;
  int b = (int)(bs / Sx);
  int tok = tokens[bs];
  int dd = d & ~1;  // even pair index (2i)
  float arg = (float)b * expf((float)dd * (-logf(10000.0f) / (float)Dx));
  float pe = (d & 1) ? cosf(arg) : sinf(arg);
  float v = emb[(size_t)tok * Dx + d] + pe;
  x[i] = v;
  xb[i] = (__bf16)v;
}

// ---------------- batched W[K,N] fp32 -> Wt[N,K] bf16 (32x32 tile transpose, z=layer) ----------------
__global__ void transpose_to_bf16(const float* __restrict__ W, __bf16* __restrict__ Wt,
                                  int K, int N, size_t sstride, size_t dstride) {
  __shared__ float tile[32][33];
  const float* Ws = W + blockIdx.z * sstride;
  __bf16* Wd = Wt + blockIdx.z * dstride;
  int tx = threadIdx.x, ty = threadIdx.y;  // 32 x 8
  int n0 = blockIdx.x * 32, k0 = blockIdx.y * 32;
#pragma unroll
  for (int i = 0; i < 4; ++i)
    tile[ty + 8 * i][tx] = Ws[(size_t)(k0 + ty + 8 * i) * N + n0 + tx];
  __syncthreads();
#pragma unroll
  for (int i = 0; i < 4; ++i)
    Wd[(size_t)(n0 + ty + 8 * i) * K + k0 + tx] = (__bf16)tile[tx][ty + 8 * i];
}

// bias concat for all layers: bqkv[L][3072]
__global__ void concat3_kernel(const float* __restrict__ a, const float* __restrict__ b,
                               const float* __restrict__ c, float* __restrict__ out) {
  int i = blockIdx.x * 256 + threadIdx.x;  // over Lx*3072
  int l = i / 3072, j = i % 3072;
  float v = (j < 1024) ? a[l * 1024 + j]
                       : ((j < 2048) ? b[l * 1024 + j - 1024] : c[l * 1024 + j - 2048]);
  out[i] = v;
}

// ---------------- V pre-transpose: qkvb[M][3072] (V at +2048) -> Vt[(b*H+h)*64+dk][S] ----------------
__global__ void transpose_v(const __bf16* __restrict__ qkvb, __bf16* __restrict__ Vt) {
  __shared__ __bf16 tile[32][40];
  int s0 = blockIdx.x * 32;
  int d0 = (blockIdx.y & 1) * 32;
  int h = blockIdx.y >> 1, b = blockIdx.z;
  int tx = threadIdx.x, ty = threadIdx.y;  // 32 x 8
  const __bf16* src = qkvb + ((size_t)b * Sx + s0) * 3072 + 2048 + h * 64 + d0;
#pragma unroll
  for (int i = 0; i < 4; ++i)
    tile[ty + 8 * i][tx] = src[(size_t)(ty + 8 * i) * 3072 + tx];
  __syncthreads();
  __bf16* dst = Vt + ((size_t)(b * Hx + h) * 64 + d0) * Sx + s0;
#pragma unroll
  for (int i = 0; i < 4; ++i)
    dst[(size_t)(ty + 8 * i) * Sx + tx] = tile[tx][ty + 8 * i];
}

// ---------------- bf16 MFMA GEMM: C = A[M,K] @ Bt[N,K]^T + bias ----------------
__device__ __forceinline__ void gld_lds16(const void* g, void* l) {
  __builtin_amdgcn_global_load_lds(
      (const __attribute__((address_space(1))) void*)(uintptr_t)g,
      (__attribute__((address_space(3))) void*)(uintptr_t)l, 16, 0, 0);
}

template <int TM, bool RELU, typename OutT>
__global__ __launch_bounds__(256) void gemm_bt(const __bf16* __restrict__ A,
                                               const __bf16* __restrict__ Bt,
                                               const float* __restrict__ bias,
                                               OutT* __restrict__ C,
                                               int K, int ldc) {
  constexpr int MI = TM / 32;            // MFMA row-tiles per wave
  constexpr int NCH = (TM + 128) / 16;   // 1KB staging chunks per K-step
  __shared__ __align__(16) __bf16 lds[(TM + 128) * 32];
  const int t = threadIdx.x;
  const int w = t >> 6, lane = t & 63;
  const int m0 = blockIdx.y * TM, n0 = blockIdx.x * 128;
  const int lr = lane >> 2, lc = (lane & 3) * 8;  // staging: row-in-chunk, k-col

  f32x4 acc[MI][4] = {};

  const int WR = (w >> 1) * (TM / 2);
  const int WC = (w & 1) * 64;
  const __bf16* Abase = A + (size_t)m0 * K;
  const __bf16* Bbase = Bt + (size_t)n0 * K;

  for (int k0 = 0; k0 < K; k0 += 32) {
    __syncthreads();
#pragma unroll
    for (int c = 0; c < NCH / 4; ++c) {
      const int ch = c * 4 + w;
      const int r = ch * 16 + lr;
      const __bf16* g = (r < TM) ? (Abase + (size_t)r * K + k0 + lc)
                                 : (Bbase + (size_t)(r - TM) * K + k0 + lc);
      gld_lds16(g, (void*)(lds + ch * 512));
    }
    __syncthreads();
    bf16x8 af[MI], bfr[4];
#pragma unroll
    for (int i = 0; i < MI; ++i)
      af[i] = *(const bf16x8*)&lds[(WR + i * 16 + (lane & 15)) * 32 + (lane >> 4) * 8];
#pragma unroll
    for (int j = 0; j < 4; ++j)
      bfr[j] = *(const bf16x8*)&lds[(TM + WC + j * 16 + (lane & 15)) * 32 + (lane >> 4) * 8];
#pragma unroll
    for (int i = 0; i < MI; ++i)
#pragma unroll
      for (int j = 0; j < 4; ++j)
        acc[i][j] = __builtin_amdgcn_mfma_f32_16x16x32_bf16(af[i], bfr[j], acc[i][j], 0, 0, 0);
  }

  // epilogue: C/D layout col=lane&15, row=(lane>>4)*4+reg (m89/m91-verified)
  const int col0 = n0 + WC + (lane & 15);
#pragma unroll
  for (int j = 0; j < 4; ++j) {
    const int n = col0 + j * 16;
    const float bn = bias[n];
#pragma unroll
    for (int i = 0; i < MI; ++i) {
#pragma unroll
      for (int r = 0; r < 4; ++r) {
        const int m = m0 + WR + i * 16 + (lane >> 4) * 4 + r;
        float v = acc[i][j][r] + bn;
        if (RELU) v = fmaxf(v, 0.f);
        C[(size_t)m * ldc + n] = (OutT)v;
      }
    }
  }
}

// ---------------- barrier-free MFMA flash attention ----------------
// grid (S/64, H, B), 256 threads (4 independent waves, 16 queries each).
// K fragments direct from global (L1/L2-resident tiles); V from pre-transposed Vt.
// Softmax without max-subtraction (scores bounded; exp/sum is shift-invariant),
// exp2 with folded 0.125*log2(e) scale, l-reduction deferred to epilogue.
__global__ __launch_bounds__(256) void attention_mfma(const __bf16* __restrict__ QKV,
                                                      const __bf16* __restrict__ Vt,
                                                      __bf16* __restrict__ O) {
  __shared__ __align__(16) __bf16 Pl[64 * 72];  // wave-private rows: [q][key]+pad

  const int t = threadIdx.x;
  const int w = t >> 6, lane = t & 63;
  const int quad = lane >> 4, l16 = lane & 15;
  const int q0 = blockIdx.x * 64;
  const int h = blockIdx.y, b = blockIdx.z;
  const size_t rowbase = (size_t)b * Sx;
  const int hoff = h * 64;

  // Q fragments: A[m=l16][k=quad*8+j], in registers for the whole kernel
  const __bf16* qrow = QKV + (rowbase + q0 + w * 16 + l16) * 3072 + hoff;
  bf16x8 qf0 = *(const bf16x8*)(qrow + quad * 8);
  bf16x8 qf1 = *(const bf16x8*)(qrow + 32 + quad * 8);

  const __bf16* Kbase = QKV + rowbase * 3072 + 1024 + hoff;
  const __bf16* Vbase = Vt + (size_t)(b * Hx + h) * 64 * Sx;

  f32x4 oacc[4] = {};
  f32x4 lacc = {0.f, 0.f, 0.f, 0.f};
  const float c = 0.125f * 1.44269504089f;  // fold 1/sqrt(64) and log2(e)

  for (int kt = 0; kt < Sx / 64; ++kt) {
    const int k0 = kt * 64;

    // QK^T: B-fragments straight from global K rows
    f32x4 s[4] = {};
#pragma unroll
    for (int j = 0; j < 4; ++j) {
      const __bf16* kr = Kbase + (size_t)(k0 + j * 16 + l16) * 3072 + quad * 8;
      bf16x8 b0 = *(const bf16x8*)kr;
      bf16x8 b1 = *(const bf16x8*)(kr + 32);
      s[j] = __builtin_amdgcn_mfma_f32_16x16x32_bf16(qf0, b0, s[j], 0, 0, 0);
      s[j] = __builtin_amdgcn_mfma_f32_16x16x32_bf16(qf1, b1, s[j], 0, 0, 0);
    }

    // p = exp2(s*c); accumulate per-lane partial row sums
#pragma unroll
    for (int j = 0; j < 4; ++j) {
#pragma unroll
      for (int r = 0; r < 4; ++r) s[j][r] = __builtin_exp2f(s[j][r] * c);
      lacc += s[j];
    }

    // P: C-layout -> wave-private LDS rows (no barrier; DS in-order per wave)
#pragma unroll
    for (int r = 0; r < 4; ++r) {
      const int prow = (w * 16 + quad * 4 + r) * 72;
#pragma unroll
      for (int j = 0; j < 4; ++j) Pl[prow + j * 16 + l16] = (__bf16)s[j][r];
    }
    bf16x8 pa0 = *(const bf16x8*)&Pl[(w * 16 + l16) * 72 + quad * 8];
    bf16x8 pa1 = *(const bf16x8*)&Pl[(w * 16 + l16) * 72 + 32 + quad * 8];

    // PV: B-fragments straight from global Vt rows
#pragma unroll
    for (int j = 0; j < 4; ++j) {
      const __bf16* vr = Vbase + (size_t)(j * 16 + l16) * Sx + k0 + quad * 8;
      bf16x8 vb0 = *(const bf16x8*)vr;
      bf16x8 vb1 = *(const bf16x8*)(vr + 32);
      oacc[j] = __builtin_amdgcn_mfma_f32_16x16x32_bf16(pa0, vb0, oacc[j], 0, 0, 0);
      oacc[j] = __builtin_amdgcn_mfma_f32_16x16x32_bf16(pa1, vb1, oacc[j], 0, 0, 0);
    }
  }

  // epilogue: reduce l across the 16-lane column group, divide, write bf16
#pragma unroll
  for (int r = 0; r < 4; ++r) {
    float lr = lacc[r];
    lr += __shfl_xor(lr, 1);
    lr += __shfl_xor(lr, 2);
    lr += __shfl_xor(lr, 4);
    lr += __shfl_xor(lr, 8);
    const float inv = 1.f / lr;
    const size_t orow = (rowbase + q0 + w * 16 + quad * 4 + r) * 1024 + hoff;
#pragma unroll
    for (int j = 0; j < 4; ++j) O[orow + j * 16 + l16] = (__bf16)(oacc[j][r] * inv);
  }
}

// ---------------- fused residual add + LayerNorm, dual fp32+bf16 output ----------------
__global__ void add_ln_kernel(const float* __restrict__ x, const float* __restrict__ r,
                              const float* __restrict__ gamma, const float* __restrict__ beta,
                              float* __restrict__ out, __bf16* __restrict__ outb) {
  int row = blockIdx.x, t = threadIdx.x;
  __shared__ float red[256];
  const float* xr = x + (size_t)row * Dx;
  const float* rr = r + (size_t)row * Dx;
  float v[4];
  float s = 0.f;
#pragma unroll
  for (int i = 0; i < 4; ++i) {
    v[i] = xr[t + i * 256] + rr[t + i * 256];
    s += v[i];
  }
  red[t] = s;
  __syncthreads();
  for (int off = 128; off > 0; off >>= 1) {
    if (t < off) red[t] += red[t + off];
    __syncthreads();
  }
  float mu = red[0] * (1.f / Dx);
  __syncthreads();
  float vs = 0.f;
#pragma unroll
  for (int i = 0; i < 4; ++i) {
    float d = v[i] - mu;
    vs += d * d;
  }
  red[t] = vs;
  __syncthreads();
  for (int off = 128; off > 0; off >>= 1) {
    if (t < off) red[t] += red[t + off];
    __syncthreads();
  }
  float is = rsqrtf(red[0] * (1.f / Dx) + 1e-5f);
  float* orow = out + (size_t)row * Dx;
  __bf16* brow = outb + (size_t)row * Dx;
#pragma unroll
  for (int i = 0; i < 4; ++i) {
    int c = t + i * 256;
    float y = (v[i] - mu) * is * gamma[c] + beta[c];
    orow[c] = y;
    brow[c] = (__bf16)y;
  }
}

extern "C" void kernel_launch(void* const* d_in, const int* in_sizes, int n_in,
                              void* d_out, int out_size, void* d_ws, size_t ws_size,
                              hipStream_t stream) {
  const int* tokens = (const int*)d_in[0];
  const float* emb = (const float*)d_in[1];
  const float* Wq = (const float*)d_in[2];
  const float* bq = (const float*)d_in[3];
  const float* Wk = (const float*)d_in[4];
  const float* bk = (const float*)d_in[5];
  const float* Wv = (const float*)d_in[6];
  const float* bv = (const float*)d_in[7];
  const float* Wo = (const float*)d_in[8];
  const float* bo = (const float*)d_in[9];
  const float* W1 = (const float*)d_in[10];
  const float* b1 = (const float*)d_in[11];
  const float* W2 = (const float*)d_in[12];
  const float* b2 = (const float*)d_in[13];
  const float* gamma = (const float*)d_in[14];
  const float* beta = (const float*)d_in[15];

  const size_t M1 = 1024 * 1024;
  float* ws = (float*)d_ws;
  float* x = ws;                        // 2M f32
  float* tmp = ws + 2 * M1;             // 2M f32
  __bf16* bfr = (__bf16*)(ws + 4 * M1);
  __bf16* xb = bfr;                     // 2M
  __bf16* qkvb = bfr + 2 * M1;          // 6M  [2048][3072]
  __bf16* ob = bfr + 8 * M1;            // 2M
  __bf16* h1b = bfr + 10 * M1;          // 4M  [2048][2048]
  __bf16* Vt = bfr + 14 * M1;           // 2M  [B*H*64][S]
  __bf16* WqkvT = bfr + 16 * M1;        // 12M [L][3072][1024]
  __bf16* WoT = bfr + 28 * M1;          // 4M  [L][1024][1024]
  __bf16* W1T = bfr + 32 * M1;          // 8M  [L][2048][1024]
  __bf16* W2T = bfr + 40 * M1;          // 8M  [L][1024][2048]
  float* bqkv = (float*)(bfr + 48 * M1);  // [L][3072] f32

  embed_kernel<<<((size_t)Mx * Dx + 255) / 256, 256, 0, stream>>>(tokens, emb, x, xb);

  // batched weight prep for ALL layers (7 launches total)
  dim3 tb(32, 8);
  transpose_to_bf16<<<dim3(32, 32, Lx), tb, 0, stream>>>(Wq, WqkvT, Dx, Dx, M1, 3 * M1);
  transpose_to_bf16<<<dim3(32, 32, Lx), tb, 0, stream>>>(Wk, WqkvT + M1, Dx, Dx, M1, 3 * M1);
  transpose_to_bf16<<<dim3(32, 32, Lx), tb, 0, stream>>>(Wv, WqkvT + 2 * M1, Dx, Dx, M1, 3 * M1);
  transpose_to_bf16<<<dim3(32, 32, Lx), tb, 0, stream>>>(Wo, WoT, Dx, Dx, M1, M1);
  transpose_to_bf16<<<dim3(64, 32, Lx), tb, 0, stream>>>(W1, W1T, Dx, FFx, 2 * M1, 2 * M1);
  transpose_to_bf16<<<dim3(32, 64, Lx), tb, 0, stream>>>(W2, W2T, FFx, Dx, 2 * M1, 2 * M1);
  concat3_kernel<<<Lx * 12, 256, 0, stream>>>(bq, bk, bv, bqkv);

  for (int l = 0; l < Lx; ++l) {
    const __bf16* WqkvT_l = WqkvT + (size_t)l * 3 * M1;
    const __bf16* WoT_l = WoT + (size_t)l * M1;
    const __bf16* W1T_l = W1T + (size_t)l * 2 * M1;
    const __bf16* W2T_l = W2T + (size_t)l * 2 * M1;
    const float* bqkv_l = bqkv + (size_t)l * 3072;
    const float* bo_l = bo + (size_t)l * Dx;
    const float* b1_l = b1 + (size_t)l * FFx;
    const float* b2_l = b2 + (size_t)l * Dx;
    const float* g_l = gamma + (size_t)l * Dx;
    const float* be_l = beta + (size_t)l * Dx;

    gemm_bt<128, false, __bf16><<<dim3(3072 / 128, Mx / 128), 256, 0, stream>>>(
        xb, WqkvT_l, bqkv_l, qkvb, Dx, 3072);

    transpose_v<<<dim3(32, 32, Bx), tb, 0, stream>>>(qkvb, Vt);
    attention_mfma<<<dim3(Sx / 64, Hx, Bx), 256, 0, stream>>>(qkvb, Vt, ob);

    gemm_bt<64, false, float><<<dim3(Dx / 128, Mx / 64), 256, 0, stream>>>(
        ob, WoT_l, bo_l, tmp, Dx, Dx);
    add_ln_kernel<<<Mx, 256, 0, stream>>>(x, tmp, g_l, be_l, x, xb);

    gemm_bt<128, true, __bf16><<<dim3(FFx / 128, Mx / 128), 256, 0, stream>>>(
        xb, W1T_l, b1_l, h1b, Dx, FFx);
    gemm_bt<64, false, float><<<dim3(Dx / 128, Mx / 64), 256, 0, stream>>>(
        h1b, W2T_l, b2_l, tmp, FFx, Dx);
    add_ln_kernel<<<Mx, 256, 0, stream>>>(x, tmp, g_l, be_l,
                                          (l == Lx - 1) ? (float*)d_out : x, xb);
  }
}

// Round 6
// 824.124 us; speedup vs baseline: 1.2711x; 1.2711x over previous
//
#include <hip/hip_runtime.h>
#include <cstdint>
#include <cstddef>

#define Bx 2
#define Sx 1024
#define Dx 1024
#define Hx 16
#define Lx 4
#define FFx 2048
#define DKx 64
#define Mx (Bx * Sx)   // 2048 rows

typedef __attribute__((ext_vector_type(4))) float f32x4;
typedef __attribute__((ext_vector_type(8))) __bf16 bf16x8;

// ---------------- embed + positional encoding (pe indexed by BATCH, per ref bug) ----------------
__global__ void embed_kernel(const int* __restrict__ tokens,
                             const float* __restrict__ emb,
                             float* __restrict__ x, __bf16* __restrict__ xb) {
  size_t i = (size_t)blockIdx.x * blockDim.x + threadIdx.x;  // over Mx*Dx
  if (i >= (size_t)Mx * Dx) return;
  int d = (int)(i % Dx);
  size_t bs = i / Dx;
  int b = (int)(bs / Sx);
  int tok = tokens[bs];
  int dd = d & ~1;  // even pair index (2i)
  float arg = (float)b * expf((float)dd * (-logf(10000.0f) / (float)Dx));
  float pe = (d & 1) ? cosf(arg) : sinf(arg);
  float v = emb[(size_t)tok * Dx + d] + pe;
  x[i] = v;
  xb[i] = (__bf16)v;
}

// ---------------- batched W[K,N] fp32 -> Wt[N,K] bf16 (32x32 tile transpose, z=layer) ----------------
__global__ void transpose_to_bf16(const float* __restrict__ W, __bf16* __restrict__ Wt,
                                  int K, int N, size_t sstride, size_t dstride) {
  __shared__ float tile[32][33];
  const float* Ws = W + blockIdx.z * sstride;
  __bf16* Wd = Wt + blockIdx.z * dstride;
  int tx = threadIdx.x, ty = threadIdx.y;  // 32 x 8
  int n0 = blockIdx.x * 32, k0 = blockIdx.y * 32;
#pragma unroll
  for (int i = 0; i < 4; ++i)
    tile[ty + 8 * i][tx] = Ws[(size_t)(k0 + ty + 8 * i) * N + n0 + tx];
  __syncthreads();
#pragma unroll
  for (int i = 0; i < 4; ++i)
    Wd[(size_t)(n0 + ty + 8 * i) * K + k0 + tx] = (__bf16)tile[tx][ty + 8 * i];
}

// bias concat for all layers: bqkv[L][3072]
__global__ void concat3_kernel(const float* __restrict__ a, const float* __restrict__ b,
                               const float* __restrict__ c, float* __restrict__ out) {
  int i = blockIdx.x * 256 + threadIdx.x;  // over Lx*3072
  int l = i / 3072, j = i % 3072;
  float v = (j < 1024) ? a[l * 1024 + j]
                       : ((j < 2048) ? b[l * 1024 + j - 1024] : c[l * 1024 + j - 2048]);
  out[i] = v;
}

// ---------------- V pre-transpose: qkvb[M][3072] (V at +2048) -> Vt[(b*H+h)*64+dk][S] ----------------
__global__ void transpose_v(const __bf16* __restrict__ qkvb, __bf16* __restrict__ Vt) {
  __shared__ __bf16 tile[32][40];
  int s0 = blockIdx.x * 32;
  int d0 = (blockIdx.y & 1) * 32;
  int h = blockIdx.y >> 1, b = blockIdx.z;
  int tx = threadIdx.x, ty = threadIdx.y;  // 32 x 8
  const __bf16* src = qkvb + ((size_t)b * Sx + s0) * 3072 + 2048 + h * 64 + d0;
#pragma unroll
  for (int i = 0; i < 4; ++i)
    tile[ty + 8 * i][tx] = src[(size_t)(ty + 8 * i) * 3072 + tx];
  __syncthreads();
  __bf16* dst = Vt + ((size_t)(b * Hx + h) * 64 + d0) * Sx + s0;
#pragma unroll
  for (int i = 0; i < 4; ++i)
    dst[(size_t)(ty + 8 * i) * Sx + tx] = tile[tx][ty + 8 * i];
}

// ---------------- bf16 MFMA GEMM: C = A[M,K] @ Bt[N,K]^T + bias ----------------
// TMxTN tile, BK=32, 4 waves, MI=2/NJ=4 each. Optional split-K via gridDim.z
// (z=1 writes C1, bias only on z=0). Kstep = per-split K; Kld = row stride.
__device__ __forceinline__ void gld_lds16(const void* g, void* l) {
  __builtin_amdgcn_global_load_lds(
      (const __attribute__((address_space(1))) void*)(uintptr_t)g,
      (__attribute__((address_space(3))) void*)(uintptr_t)l, 16, 0, 0);
}

template <int TM, int TN, bool RELU, typename OutT>
__global__ __launch_bounds__(256) void gemm_bt(const __bf16* __restrict__ A,
                                               const __bf16* __restrict__ Bt,
                                               const float* __restrict__ bias,
                                               OutT* __restrict__ C0,
                                               float* __restrict__ C1,
                                               int Kstep, int Kld, int ldc) {
  static_assert((TM + TN) == 192, "NCH fixed at 12");
  __shared__ __align__(16) __bf16 lds[(TM + TN) * 32];
  const int t = threadIdx.x;
  const int w = t >> 6, lane = t & 63;
  const int quad = lane >> 4, l16 = lane & 15;
  const int m0 = blockIdx.y * TM, n0 = blockIdx.x * TN;
  const int lr = lane >> 2, lc = (lane & 3) * 8;  // staging: row-in-chunk, k-col
  const int koff = blockIdx.z * Kstep;

  f32x4 acc[2][4] = {};

  const int WR = (TN == 128) ? (w >> 1) * (TM / 2) : w * (TM / 4);
  const int WC = (TN == 128) ? (w & 1) * 64 : 0;
  const __bf16* Abase = A + (size_t)m0 * Kld + koff;
  const __bf16* Bbase = Bt + (size_t)n0 * Kld + koff;

  for (int k0 = 0; k0 < Kstep; k0 += 32) {
    __syncthreads();
#pragma unroll
    for (int c = 0; c < 3; ++c) {
      const int ch = c * 4 + w;
      const int r = ch * 16 + lr;
      const __bf16* g = (r < TM) ? (Abase + (size_t)r * Kld + k0 + lc)
                                 : (Bbase + (size_t)(r - TM) * Kld + k0 + lc);
      gld_lds16(g, (void*)(lds + ch * 512));
    }
    __syncthreads();
    bf16x8 af[2], bfr[4];
#pragma unroll
    for (int i = 0; i < 2; ++i)
      af[i] = *(const bf16x8*)&lds[(WR + i * 16 + l16) * 32 + quad * 8];
#pragma unroll
    for (int j = 0; j < 4; ++j)
      bfr[j] = *(const bf16x8*)&lds[(TM + WC + j * 16 + l16) * 32 + quad * 8];
#pragma unroll
    for (int i = 0; i < 2; ++i)
#pragma unroll
      for (int j = 0; j < 4; ++j)
        acc[i][j] = __builtin_amdgcn_mfma_f32_16x16x32_bf16(af[i], bfr[j], acc[i][j], 0, 0, 0);
  }

  // epilogue: C/D layout col=lane&15, row=(lane>>4)*4+reg (m89/m91-verified)
  const bool z0 = (blockIdx.z == 0);
  const int col0 = n0 + WC + l16;
#pragma unroll
  for (int j = 0; j < 4; ++j) {
    const int n = col0 + j * 16;
    const float bn = z0 ? bias[n] : 0.f;
#pragma unroll
    for (int i = 0; i < 2; ++i) {
#pragma unroll
      for (int r = 0; r < 4; ++r) {
        const int m = m0 + WR + i * 16 + quad * 4 + r;
        float v = acc[i][j][r] + bn;
        if (RELU) v = fmaxf(v, 0.f);
        if (z0)
          C0[(size_t)m * ldc + n] = (OutT)v;
        else
          C1[(size_t)m * ldc + n] = v;
      }
    }
  }
}

// ---------------- MFMA flash attention: padded double-buffered LDS staging ----------------
// grid (S/64, H, B), 256 threads (4 waves x 16 queries). One barrier per K-tile;
// tile kt+1 global loads prefetched into regs during tile kt compute.
// Softmax without max-subtraction (scores bounded), exp2 w/ folded scale,
// l-reduction deferred to epilogue.
__global__ __launch_bounds__(256) void attention_mfma(const __bf16* __restrict__ QKV,
                                                      const __bf16* __restrict__ Vt,
                                                      __bf16* __restrict__ O) {
  __shared__ __align__(16) __bf16 Ks[2][64 * 72];  // [key][dk], stride 72 (bank-uniform)
  __shared__ __align__(16) __bf16 Vs[2][64 * 72];  // [dk][key], stride 72
  __shared__ __align__(16) __bf16 Pl[64 * 72];     // wave-private rows: [q][key]

  const int t = threadIdx.x;
  const int w = t >> 6, lane = t & 63;
  const int quad = lane >> 4, l16 = lane & 15;
  const int q0 = blockIdx.x * 64;
  const int h = blockIdx.y, b = blockIdx.z;
  const size_t rowbase = (size_t)b * Sx;
  const int hoff = h * 64;

  // Q fragments: A[m=l16][k=quad*8+j], in registers for the whole kernel
  const __bf16* qrow = QKV + (rowbase + q0 + w * 16 + l16) * 3072 + hoff;
  bf16x8 qf0 = *(const bf16x8*)(qrow + quad * 8);
  bf16x8 qf1 = *(const bf16x8*)(qrow + 32 + quad * 8);

  const __bf16* Kbase = QKV + rowbase * 3072 + 1024 + hoff;
  const __bf16* Vbase = Vt + (size_t)(b * Hx + h) * 64 * Sx;

  // staging role: thread t covers row srow, 32B segment sseg (coalesced 128B/4 lanes)
  const int srow = t >> 2, sseg = t & 3;
  bf16x8 kp0, kp1, vp0, vp1;

  f32x4 oacc[4] = {};
  f32x4 lacc = {0.f, 0.f, 0.f, 0.f};
  const float cs = 0.125f * 1.44269504089f;  // fold 1/sqrt(64) and log2(e)

  // prologue: stage tile 0
  {
    const __bf16* kr = Kbase + (size_t)srow * 3072 + sseg * 16;
    kp0 = *(const bf16x8*)kr;
    kp1 = *(const bf16x8*)(kr + 8);
    const __bf16* vr = Vbase + (size_t)srow * Sx + sseg * 16;
    vp0 = *(const bf16x8*)vr;
    vp1 = *(const bf16x8*)(vr + 8);
    *(bf16x8*)&Ks[0][srow * 72 + sseg * 16] = kp0;
    *(bf16x8*)&Ks[0][srow * 72 + sseg * 16 + 8] = kp1;
    *(bf16x8*)&Vs[0][srow * 72 + sseg * 16] = vp0;
    *(bf16x8*)&Vs[0][srow * 72 + sseg * 16 + 8] = vp1;
  }
  __syncthreads();

  for (int kt = 0; kt < Sx / 64; ++kt) {
    const int cur = kt & 1;
    // prefetch next tile into regs (lands during this tile's compute)
    if (kt < Sx / 64 - 1) {
      const int kn = (kt + 1) * 64;
      const __bf16* kr = Kbase + (size_t)(kn + srow) * 3072 + sseg * 16;
      kp0 = *(const bf16x8*)kr;
      kp1 = *(const bf16x8*)(kr + 8);
      const __bf16* vr = Vbase + (size_t)srow * Sx + kn + sseg * 16;
      vp0 = *(const bf16x8*)vr;
      vp1 = *(const bf16x8*)(vr + 8);
    }

    // QK^T: B-fragments from padded LDS
    f32x4 s[4] = {};
#pragma unroll
    for (int j = 0; j < 4; ++j) {
      bf16x8 b0 = *(const bf16x8*)&Ks[cur][(j * 16 + l16) * 72 + quad * 8];
      bf16x8 b1 = *(const bf16x8*)&Ks[cur][(j * 16 + l16) * 72 + 32 + quad * 8];
      s[j] = __builtin_amdgcn_mfma_f32_16x16x32_bf16(qf0, b0, s[j], 0, 0, 0);
      s[j] = __builtin_amdgcn_mfma_f32_16x16x32_bf16(qf1, b1, s[j], 0, 0, 0);
    }

    // p = exp2(s*cs); accumulate per-lane partial row sums
#pragma unroll
    for (int j = 0; j < 4; ++j) {
#pragma unroll
      for (int r = 0; r < 4; ++r) s[j][r] = __builtin_exp2f(s[j][r] * cs);
      lacc += s[j];
    }

    // P: C-layout -> wave-private LDS rows (no barrier; DS in-order per wave)
#pragma unroll
    for (int r = 0; r < 4; ++r) {
      const int prow = (w * 16 + quad * 4 + r) * 72;
#pragma unroll
      for (int j = 0; j < 4; ++j) Pl[prow + j * 16 + l16] = (__bf16)s[j][r];
    }
    bf16x8 pa0 = *(const bf16x8*)&Pl[(w * 16 + l16) * 72 + quad * 8];
    bf16x8 pa1 = *(const bf16x8*)&Pl[(w * 16 + l16) * 72 + 32 + quad * 8];

    // PV: B-fragments from padded LDS
#pragma unroll
    for (int j = 0; j < 4; ++j) {
      bf16x8 vb0 = *(const bf16x8*)&Vs[cur][(j * 16 + l16) * 72 + quad * 8];
      bf16x8 vb1 = *(const bf16x8*)&Vs[cur][(j * 16 + l16) * 72 + 32 + quad * 8];
      oacc[j] = __builtin_amdgcn_mfma_f32_16x16x32_bf16(pa0, vb0, oacc[j], 0, 0, 0);
      oacc[j] = __builtin_amdgcn_mfma_f32_16x16x32_bf16(pa1, vb1, oacc[j], 0, 0, 0);
    }

    // write prefetched tile into the other buffer (its readers synced last barrier)
    if (kt < Sx / 64 - 1) {
      const int nxt = 1 - cur;
      *(bf16x8*)&Ks[nxt][srow * 72 + sseg * 16] = kp0;
      *(bf16x8*)&Ks[nxt][srow * 72 + sseg * 16 + 8] = kp1;
      *(bf16x8*)&Vs[nxt][srow * 72 + sseg * 16] = vp0;
      *(bf16x8*)&Vs[nxt][srow * 72 + sseg * 16 + 8] = vp1;
    }
    __syncthreads();
  }

  // epilogue: reduce l across the 16-lane column group, divide, write bf16
#pragma unroll
  for (int r = 0; r < 4; ++r) {
    float lr = lacc[r];
    lr += __shfl_xor(lr, 1);
    lr += __shfl_xor(lr, 2);
    lr += __shfl_xor(lr, 4);
    lr += __shfl_xor(lr, 8);
    const float inv = 1.f / lr;
    const size_t orow = (rowbase + q0 + w * 16 + quad * 4 + r) * 1024 + hoff;
#pragma unroll
    for (int j = 0; j < 4; ++j) O[orow + j * 16 + l16] = (__bf16)(oacc[j][r] * inv);
  }
}

// ---------------- fused residual add (x + r0 + r1) + LayerNorm, dual fp32+bf16 out ----------------
__global__ void add_ln_kernel(const float* __restrict__ x, const float* __restrict__ r0,
                              const float* __restrict__ r1,
                              const float* __restrict__ gamma, const float* __restrict__ beta,
                              float* __restrict__ out, __bf16* __restrict__ outb) {
  int row = blockIdx.x, t = threadIdx.x;
  __shared__ float red[256];
  const float* xr = x + (size_t)row * Dx;
  const float* rr0 = r0 + (size_t)row * Dx;
  const float* rr1 = r1 + (size_t)row * Dx;
  float v[4];
  float s = 0.f;
#pragma unroll
  for (int i = 0; i < 4; ++i) {
    int c = t + i * 256;
    v[i] = xr[c] + rr0[c] + rr1[c];
    s += v[i];
  }
  red[t] = s;
  __syncthreads();
  for (int off = 128; off > 0; off >>= 1) {
    if (t < off) red[t] += red[t + off];
    __syncthreads();
  }
  float mu = red[0] * (1.f / Dx);
  __syncthreads();
  float vs = 0.f;
#pragma unroll
  for (int i = 0; i < 4; ++i) {
    float d = v[i] - mu;
    vs += d * d;
  }
  red[t] = vs;
  __syncthreads();
  for (int off = 128; off > 0; off >>= 1) {
    if (t < off) red[t] += red[t + off];
    __syncthreads();
  }
  float is = rsqrtf(red[0] * (1.f / Dx) + 1e-5f);
  float* orow = out + (size_t)row * Dx;
  __bf16* brow = outb + (size_t)row * Dx;
#pragma unroll
  for (int i = 0; i < 4; ++i) {
    int c = t + i * 256;
    float y = (v[i] - mu) * is * gamma[c] + beta[c];
    orow[c] = y;
    brow[c] = (__bf16)y;
  }
}

extern "C" void kernel_launch(void* const* d_in, const int* in_sizes, int n_in,
                              void* d_out, int out_size, void* d_ws, size_t ws_size,
                              hipStream_t stream) {
  const int* tokens = (const int*)d_in[0];
  const float* emb = (const float*)d_in[1];
  const float* Wq = (const float*)d_in[2];
  const float* bq = (const float*)d_in[3];
  const float* Wk = (const float*)d_in[4];
  const float* bk = (const float*)d_in[5];
  const float* Wv = (const float*)d_in[6];
  const float* bv = (const float*)d_in[7];
  const float* Wo = (const float*)d_in[8];
  const float* bo = (const float*)d_in[9];
  const float* W1 = (const float*)d_in[10];
  const float* b1 = (const float*)d_in[11];
  const float* W2 = (const float*)d_in[12];
  const float* b2 = (const float*)d_in[13];
  const float* gamma = (const float*)d_in[14];
  const float* beta = (const float*)d_in[15];

  const size_t M1 = 1024 * 1024;
  float* ws = (float*)d_ws;
  float* x = ws;                        // 2M f32
  float* tmp = ws + 2 * M1;             // 2M f32 (split-K partial 0)
  __bf16* bfr = (__bf16*)(ws + 4 * M1);
  __bf16* xb = bfr;                     // 2M
  __bf16* qkvb = bfr + 2 * M1;          // 6M  [2048][3072]
  __bf16* ob = bfr + 8 * M1;            // 2M
  __bf16* h1b = bfr + 10 * M1;          // 4M  [2048][2048]
  __bf16* Vt = bfr + 14 * M1;           // 2M  [B*H*64][S]
  __bf16* WqkvT = bfr + 16 * M1;        // 12M [L][3072][1024]
  __bf16* WoT = bfr + 28 * M1;          // 4M  [L][1024][1024]
  __bf16* W1T = bfr + 32 * M1;          // 8M  [L][2048][1024]
  __bf16* W2T = bfr + 40 * M1;          // 8M  [L][1024][2048]
  float* bqkv = (float*)(bfr + 48 * M1);  // [L][3072] f32
  float* tmp1 = (float*)qkvb;           // split-K partial 1 (qkvb free during Wo/FF2)

  embed_kernel<<<((size_t)Mx * Dx + 255) / 256, 256, 0, stream>>>(tokens, emb, x, xb);

  // batched weight prep for ALL layers (7 launches total)
  dim3 tb(32, 8);
  transpose_to_bf16<<<dim3(32, 32, Lx), tb, 0, stream>>>(Wq, WqkvT, Dx, Dx, M1, 3 * M1);
  transpose_to_bf16<<<dim3(32, 32, Lx), tb, 0, stream>>>(Wk, WqkvT + M1, Dx, Dx, M1, 3 * M1);
  transpose_to_bf16<<<dim3(32, 32, Lx), tb, 0, stream>>>(Wv, WqkvT + 2 * M1, Dx, Dx, M1, 3 * M1);
  transpose_to_bf16<<<dim3(32, 32, Lx), tb, 0, stream>>>(Wo, WoT, Dx, Dx, M1, M1);
  transpose_to_bf16<<<dim3(64, 32, Lx), tb, 0, stream>>>(W1, W1T, Dx, FFx, 2 * M1, 2 * M1);
  transpose_to_bf16<<<dim3(32, 64, Lx), tb, 0, stream>>>(W2, W2T, FFx, Dx, 2 * M1, 2 * M1);
  concat3_kernel<<<Lx * 12, 256, 0, stream>>>(bq, bk, bv, bqkv);

  for (int l = 0; l < Lx; ++l) {
    const __bf16* WqkvT_l = WqkvT + (size_t)l * 3 * M1;
    const __bf16* WoT_l = WoT + (size_t)l * M1;
    const __bf16* W1T_l = W1T + (size_t)l * 2 * M1;
    const __bf16* W2T_l = W2T + (size_t)l * 2 * M1;
    const float* bqkv_l = bqkv + (size_t)l * 3072;
    const float* bo_l = bo + (size_t)l * Dx;
    const float* b1_l = b1 + (size_t)l * FFx;
    const float* b2_l = b2 + (size_t)l * Dx;
    const float* g_l = gamma + (size_t)l * Dx;
    const float* be_l = beta + (size_t)l * Dx;

    // QKV: 128x64 tiles -> 768 blocks (3/CU)
    gemm_bt<128, 64, false, __bf16><<<dim3(3072 / 64, Mx / 128, 1), 256, 0, stream>>>(
        xb, WqkvT_l, bqkv_l, qkvb, nullptr, Dx, Dx, 3072);

    transpose_v<<<dim3(32, 32, Bx), tb, 0, stream>>>(qkvb, Vt);
    attention_mfma<<<dim3(Sx / 64, Hx, Bx), 256, 0, stream>>>(qkvb, Vt, ob);

    // Wo: 64x128 tiles, split-K=2 -> 512 blocks (2/CU); partials in tmp/tmp1
    gemm_bt<64, 128, false, float><<<dim3(Dx / 128, Mx / 64, 2), 256, 0, stream>>>(
        ob, WoT_l, bo_l, tmp, tmp1, Dx / 2, Dx, Dx);
    add_ln_kernel<<<Mx, 256, 0, stream>>>(x, tmp, tmp1, g_l, be_l, x, xb);

    // FF1: 128x64 tiles -> 512 blocks (2/CU)
    gemm_bt<128, 64, true, __bf16><<<dim3(FFx / 64, Mx / 128, 1), 256, 0, stream>>>(
        xb, W1T_l, b1_l, h1b, nullptr, Dx, Dx, FFx);
    // FF2: 64x128 tiles, split-K=2 -> 512 blocks
    gemm_bt<64, 128, false, float><<<dim3(Dx / 128, Mx / 64, 2), 256, 0, stream>>>(
        h1b, W2T_l, b2_l, tmp, tmp1, FFx / 2, FFx, Dx);
    add_ln_kernel<<<Mx, 256, 0, stream>>>(x, tmp, tmp1, g_l, be_l,
                                          (l == Lx - 1) ? (float*)d_out : x, xb);
  }
}